// Round 4
// baseline (303.109 us; speedup 1.0000x reference)
//
#include <hip/hip_runtime.h>

#define HH 512
#define WW 512
#define HW (HH * WW)

typedef float f32x4 __attribute__((ext_vector_type(4)));

// ---------------- Pass 1: partial sums per (plane, strip) ----------------
// grid = 512 planes * 4 strips, block = 256 threads. float4 loads.
// Plane order INCREASING: leaves the tail of x resident in LLC for conv.
__global__ __launch_bounds__(256) void pool_kernel(const float* __restrict__ x,
                                                   float* __restrict__ partial) {
    const int blk = blockIdx.x;
    const int plane = blk >> 2;
    const int strip = blk & 3;
    const float4* p = reinterpret_cast<const float4*>(x + (size_t)plane * HW) +
                      (size_t)strip * (HW / 16);
    float s = 0.f;
    #pragma unroll 4
    for (int i = threadIdx.x; i < HW / 16; i += 256) {
        float4 v = p[i];
        s += (v.x + v.y) + (v.z + v.w);
    }
    // wave(64) reduce
    #pragma unroll
    for (int off = 32; off > 0; off >>= 1) s += __shfl_down(s, off, 64);
    __shared__ float wsum[4];
    const int lane = threadIdx.x & 63;
    const int wid  = threadIdx.x >> 6;
    if (lane == 0) wsum[wid] = s;
    __syncthreads();
    if (threadIdx.x == 0) partial[blk] = (wsum[0] + wsum[1]) + (wsum[2] + wsum[3]);
}

// ---------------- Pass 2: tiny SEKG head, one block ----------------
__global__ __launch_bounds__(512) void make_kernels(const float* __restrict__ partial,
                                                    const float* __restrict__ w1,
                                                    const float* __restrict__ b1,
                                                    const float* __restrict__ w2,
                                                    const float* __restrict__ b2,
                                                    float* __restrict__ kout) {
    __shared__ float feat[512];  // [b][c]
    __shared__ float h1[512];    // [b][c]
    __shared__ float kr[72];     // [b][9]
    __shared__ float ksum[8];
    const int t = threadIdx.x;  // 0..511
    feat[t] = (partial[4*t] + partial[4*t+1] + partial[4*t+2] + partial[4*t+3]) *
              (1.0f / (float)HW);
    __syncthreads();
    const int b = t >> 6, j = t & 63;
    float s = b1[j];
    const float* wr = w1 + j * 64;
    const float* fb = feat + b * 64;
    #pragma unroll 8
    for (int c = 0; c < 64; ++c) s += fb[c] * wr[c];
    h1[t] = (s > 0.f) ? s : 0.2f * s;  // LeakyReLU(0.2)
    __syncthreads();
    if (t < 72) {
        const int bb = t / 9, q = t - bb * 9;
        float s2 = b2[q];
        const float* hb = h1 + bb * 64;
        const float* wq = w2 + q * 64;
        #pragma unroll 8
        for (int c = 0; c < 64; ++c) s2 += hb[c] * wq[c];
        kr[t] = s2;
    }
    __syncthreads();
    if (t < 8) {
        float s3 = 0.f;
        #pragma unroll
        for (int q = 0; q < 9; ++q) s3 += kr[t * 9 + q];
        ksum[t] = s3 + 1e-6f;
    }
    __syncthreads();
    if (t < 72) kout[t] = kr[t] / ksum[t / 9];
}

// ---------------- Pass 3: depthwise 3x3 conv ----------------
// Each thread: 4-wide x 32-tall output strip, rolling 3-row register window.
// Plane order REVERSED vs pool: pool's tail (LLC-resident) is read first;
// conv's tail (planes ~0..255) then seeds the next replay's pool.
// Non-temporal stores keep out from evicting x in L2/LLC.
__device__ __forceinline__ void load_row6(float r[6], const float* __restrict__ plane,
                                          int y, int x0) {
    if ((unsigned)y >= (unsigned)HH) {
        r[0] = r[1] = r[2] = r[3] = r[4] = r[5] = 0.f;
        return;
    }
    const float* row = plane + (size_t)y * WW;
    r[0] = (x0 > 0) ? row[x0 - 1] : 0.f;
    const float4 m = *reinterpret_cast<const float4*>(row + x0);
    r[1] = m.x; r[2] = m.y; r[3] = m.z; r[4] = m.w;
    r[5] = (x0 + 4 < WW) ? row[x0 + 4] : 0.f;
}

__global__ __launch_bounds__(256) void conv_kernel(const float* __restrict__ x,
                                                   const float* __restrict__ kall,
                                                   float* __restrict__ out) {
    const int gid    = blockIdx.x * 256 + threadIdx.x;
    const int xseg   = gid & 127;             // 128 quads of 4 -> 512 wide
    const int ystrip = (gid >> 7) & 15;       // 16 strips of 32 rows
    const int plane  = 511 - (gid >> 11);     // REVERSED plane order
    const int b      = plane >> 6;
    float k[9];
    #pragma unroll
    for (int i = 0; i < 9; ++i) k[i] = kall[b * 9 + i];
    const float* xp = x + (size_t)plane * HW;
    float* op       = out + (size_t)plane * HW;
    const int x0 = xseg * 4;
    const int y0 = ystrip * 32;

    float r0[6], r1[6], r2[6];
    load_row6(r0, xp, y0 - 1, x0);
    load_row6(r1, xp, y0,     x0);
    #pragma unroll 8
    for (int i = 0; i < 32; ++i) {
        load_row6(r2, xp, y0 + i + 1, x0);
        f32x4 o;
        #pragma unroll
        for (int j = 0; j < 4; ++j) {
            o[j] = k[0]*r0[j] + k[1]*r0[j+1] + k[2]*r0[j+2]
                 + k[3]*r1[j] + k[4]*r1[j+1] + k[5]*r1[j+2]
                 + k[6]*r2[j] + k[7]*r2[j+1] + k[8]*r2[j+2];
        }
        __builtin_nontemporal_store(o,
            reinterpret_cast<f32x4*>(op + (size_t)(y0 + i) * WW + x0));
        #pragma unroll
        for (int q = 0; q < 6; ++q) { r0[q] = r1[q]; r1[q] = r2[q]; }
    }
}

extern "C" void kernel_launch(void* const* d_in, const int* in_sizes, int n_in,
                              void* d_out, int out_size, void* d_ws, size_t ws_size,
                              hipStream_t stream) {
    const float* x  = (const float*)d_in[0];
    const float* w1 = (const float*)d_in[1];
    const float* b1 = (const float*)d_in[2];
    const float* w2 = (const float*)d_in[3];
    const float* b2 = (const float*)d_in[4];
    float* out = (float*)d_out;

    float* partial = (float*)d_ws;      // 2048 floats
    float* kout    = partial + 2048;    // 72 floats

    pool_kernel<<<2048, 256, 0, stream>>>(x, partial);
    make_kernels<<<1, 512, 0, stream>>>(partial, w1, b1, w2, b2, kout);
    conv_kernel<<<4096, 256, 0, stream>>>(x, kout, out);
}

// Round 5
// 302.163 us; speedup vs baseline: 1.0031x; 1.0031x over previous
//
#include <hip/hip_runtime.h>

#define HH 512
#define WW 512
#define HW (HH * WW)

typedef float f32x4 __attribute__((ext_vector_type(4)));

// Rolling-row loader: 6-wide window (x0-1 .. x0+4), zero-padded at edges.
__device__ __forceinline__ void load_row6(float r[6], const float* __restrict__ plane,
                                          int y, int x0) {
    if ((unsigned)y >= (unsigned)HH) {
        r[0] = r[1] = r[2] = r[3] = r[4] = r[5] = 0.f;
        return;
    }
    const float* row = plane + (size_t)y * WW;
    r[0] = (x0 > 0) ? row[x0 - 1] : 0.f;
    const float4 m = *reinterpret_cast<const float4*>(row + x0);
    r[1] = m.x; r[2] = m.y; r[3] = m.z; r[4] = m.w;
    r[5] = (x0 + 4 < WW) ? row[x0 + 4] : 0.f;
}

// Pipelined stage kernel. Blocks [0, nconv): depthwise-conv batch (ib-1),
// taps computed in-block from partials written by the PREVIOUS launch
// (cross-launch => coherent). Blocks [nconv, nconv+256): pool batch ib.
// Pool reads (regular) populate LLC with batch ib (64 MiB << 256 MiB LLC);
// next launch's conv reads it as LLC hits. nt-stores keep `out` from
// evicting x.
__global__ __launch_bounds__(256) void stage_kernel(
        const float* __restrict__ x, float* __restrict__ out,
        float* __restrict__ partial,
        const float* __restrict__ w1, const float* __restrict__ b1,
        const float* __restrict__ w2, const float* __restrict__ b2,
        int ib, int nconv) {
    const int blk = blockIdx.x;
    const int t = threadIdx.x;

    if (blk < nconv) {
        // ---------- conv part: batch b = ib-1 ----------
        const int b = ib - 1;
        __shared__ float feat[64];
        __shared__ float h1s[64];
        __shared__ float kks[10];
        if (t < 64) {
            const float* p4 = partial + (size_t)(b * 64 + t) * 4;
            feat[t] = (p4[0] + p4[1] + p4[2] + p4[3]) * (1.0f / (float)HW);
        }
        __syncthreads();
        if (t < 64) {
            float s = b1[t];
            const float* wr = w1 + t * 64;
            #pragma unroll 8
            for (int c = 0; c < 64; ++c) s += feat[c] * wr[c];
            h1s[t] = (s > 0.f) ? s : 0.2f * s;  // LeakyReLU(0.2)
        }
        __syncthreads();
        if (t < 9) {
            float s2 = b2[t];
            const float* wq = w2 + t * 64;
            #pragma unroll 8
            for (int c = 0; c < 64; ++c) s2 += h1s[c] * wq[c];
            kks[t] = s2;
        }
        __syncthreads();
        if (t == 0) {
            float s3 = 0.f;
            #pragma unroll
            for (int q = 0; q < 9; ++q) s3 += kks[q];
            kks[9] = s3 + 1e-6f;
        }
        __syncthreads();
        float k[9];
        {
            const float ks = kks[9];
            #pragma unroll
            for (int q = 0; q < 9; ++q) k[q] = kks[q] / ks;
        }

        const int plane_local = blk >> 4;                 // 0..63
        const int plane = b * 64 + plane_local;
        const int xseg = t & 127;                         // 128 quads -> 512 wide
        const int ystrip = ((blk & 15) << 1) | (t >> 7);  // 32 strips of 16 rows
        const float* xp = x + (size_t)plane * HW;
        float* op       = out + (size_t)plane * HW;
        const int x0 = xseg * 4;
        const int y0 = ystrip * 16;

        float r0[6], r1[6], r2[6];
        load_row6(r0, xp, y0 - 1, x0);
        load_row6(r1, xp, y0,     x0);
        #pragma unroll
        for (int i = 0; i < 16; ++i) {
            load_row6(r2, xp, y0 + i + 1, x0);
            f32x4 o;
            #pragma unroll
            for (int j = 0; j < 4; ++j) {
                o[j] = k[0]*r0[j] + k[1]*r0[j+1] + k[2]*r0[j+2]
                     + k[3]*r1[j] + k[4]*r1[j+1] + k[5]*r1[j+2]
                     + k[6]*r2[j] + k[7]*r2[j+1] + k[8]*r2[j+2];
            }
            __builtin_nontemporal_store(o,
                reinterpret_cast<f32x4*>(op + (size_t)(y0 + i) * WW + x0));
            #pragma unroll
            for (int q = 0; q < 6; ++q) { r0[q] = r1[q]; r1[q] = r2[q]; }
        }
    } else {
        // ---------- pool part: batch ib ----------
        const int pblk = blk - nconv;                 // 0..255
        const int plane = ib * 64 + (pblk >> 2);
        const int strip = pblk & 3;
        const float4* p = reinterpret_cast<const float4*>(x + (size_t)plane * HW) +
                          (size_t)strip * (HW / 16);
        float s = 0.f;
        #pragma unroll 4
        for (int i = t; i < HW / 16; i += 256) {
            float4 v = p[i];
            s += (v.x + v.y) + (v.z + v.w);
        }
        #pragma unroll
        for (int off = 32; off > 0; off >>= 1) s += __shfl_down(s, off, 64);
        __shared__ float wsum[4];
        const int lane = t & 63;
        const int wid  = t >> 6;
        if (lane == 0) wsum[wid] = s;
        __syncthreads();
        if (t == 0)
            partial[(size_t)plane * 4 + strip] =
                (wsum[0] + wsum[1]) + (wsum[2] + wsum[3]);
    }
}

extern "C" void kernel_launch(void* const* d_in, const int* in_sizes, int n_in,
                              void* d_out, int out_size, void* d_ws, size_t ws_size,
                              hipStream_t stream) {
    const float* x  = (const float*)d_in[0];
    const float* w1 = (const float*)d_in[1];
    const float* b1 = (const float*)d_in[2];
    const float* w2 = (const float*)d_in[3];
    const float* b2 = (const float*)d_in[4];
    float* out = (float*)d_out;
    float* partial = (float*)d_ws;  // 2048 floats

    // Stage 0: pool batch 0 only.
    stage_kernel<<<256, 256, 0, stream>>>(x, out, partial, w1, b1, w2, b2, 0, 0);
    // Stages 1..7: conv(batch i-1) + pool(batch i).
    for (int i = 1; i <= 7; ++i)
        stage_kernel<<<1280, 256, 0, stream>>>(x, out, partial, w1, b1, w2, b2, i, 1024);
    // Stage 8: conv batch 7 only.
    stage_kernel<<<1024, 256, 0, stream>>>(x, out, partial, w1, b1, w2, b2, 8, 1024);
}